// Round 4
// baseline (354.194 us; speedup 1.0000x reference)
//
#include <hip/hip_runtime.h>
#include <hip/hip_bf16.h>

// Problem constants
#define NB    8
#define SQN   2048
#define SKN   4096
#define DDIM  512
#define DVDIM 256
#define NROWS (NB*SQN)      // 16384
#define NS    2             // SK splits
#define NJ    ((SKN/64)/NS) // 32 j-iterations per split (64 keys each)

typedef __attribute__((ext_vector_type(8)))  short bf16x8;   // 8 bf16 = 4 VGPRs (MFMA A/B frag)
typedef __attribute__((ext_vector_type(4)))  short bf16x4;
typedef __attribute__((ext_vector_type(4)))  float f32x4;    // 16x16 MFMA C/D frag
typedef __attribute__((ext_vector_type(16))) float f32x16;   // 32x32 MFMA C/D frag

// fp32 -> bf16 round-to-nearest-even, bit pattern as short
__device__ __forceinline__ short f2bf(float f) {
    unsigned u = __float_as_uint(f);
    return (short)((u + 0x7FFFu + ((u >> 16) & 1u)) >> 16);
}

// async global->LDS, 16B per lane; LDS dst = wave-uniform base + lane*16,
// global src is per-lane (used to pre-arrange frag-linear LDS layouts)
__device__ __forceinline__ void gload_lds16(const void* g, void* l) {
    __builtin_amdgcn_global_load_lds(
        (const __attribute__((address_space(1))) unsigned int*)g,
        (__attribute__((address_space(3))) unsigned int*)l, 16, 0, 0);
}

// counted-vmcnt barrier: waits only the oldest loads (keeps N newest in
// flight across the barrier). sched_barrier fences per rule #18.
#define BAR_VM(N_) do {                                                       \
    asm volatile("s_waitcnt vmcnt(" #N_ ")" ::: "memory");                    \
    __builtin_amdgcn_sched_barrier(0);                                        \
    __builtin_amdgcn_s_barrier();                                             \
    __builtin_amdgcn_sched_barrier(0);                                        \
} while (0)

// LDS-only barrier (P/stat exchange): vm prefetches stay in flight.
#define BAR_LGKM() do {                                                       \
    asm volatile("s_waitcnt lgkmcnt(0)" ::: "memory");                        \
    __builtin_amdgcn_sched_barrier(0);                                        \
    __builtin_amdgcn_s_barrier();                                             \
    __builtin_amdgcn_sched_barrier(0);                                        \
} while (0)

// ---------------------------------------------------------------------------
// Fused projection GEMMs, one launch. grid = (64, 8, 2).  (unchanged)
//  z=0: key[s][d]  = sum_c Y[s][c]*Wk[d][c]   M=4096 N=512
//  z=1: vt[dv][s]  = sum_c Wv[dv][c]*Z[s][c]  M=256  N=4096 (uses 256 of 512 tiles)
// ---------------------------------------------------------------------------
__global__ __launch_bounds__(256, 2) void proj_gemms(
    const float* __restrict__ Y, const float* __restrict__ Z,
    const float* __restrict__ Wk, const float* __restrict__ Wv,
    unsigned short* __restrict__ keyb, unsigned short* __restrict__ vtb)
{
    __shared__ short sA[64*128];   // 16 KB
    __shared__ short sB[64*128];   // 16 KB
    const float *A, *Bm;
    unsigned short* C;
    int N, m0, n0;
    if (blockIdx.z == 0) {
        A = Y; Bm = Wk; C = keyb; N = DDIM;
        m0 = blockIdx.x * 64; n0 = blockIdx.y * 64;
    } else {
        int lin = blockIdx.x * 8 + blockIdx.y;
        if (lin >= 256) return;                 // value GEMM needs 256 tiles
        A = Wv; Bm = Z; C = vtb; N = SKN;
        m0 = (lin >> 6) * 64; n0 = (lin & 63) * 64;
    }
    const int tid  = threadIdx.x;
    const int wave = tid >> 6;
    const int lane = tid & 63;
    const int quad = lane >> 4;
    const int l15  = lane & 15;

    f32x4 acc[4];
    #pragma unroll
    for (int n = 0; n < 4; ++n) { acc[n][0]=0.f; acc[n][1]=0.f; acc[n][2]=0.f; acc[n][3]=0.f; }

    float4 ra[8], rb[8];
    #pragma unroll
    for (int it = 0; it < 8; ++it) {            // prefetch kc=0
        int f = it*1024 + tid*4, row = f >> 7, col = f & 127;
        ra[it] = *(const float4*)(A  + (size_t)(m0+row)*DDIM + col);
        rb[it] = *(const float4*)(Bm + (size_t)(n0+row)*DDIM + col);
    }

    for (int kc = 0; kc < DDIM; kc += 128) {
        __syncthreads();                        // LDS free (prev MFMA done)
        #pragma unroll
        for (int it = 0; it < 8; ++it) {
            int f = it*1024 + tid*4;
            bf16x4 a4; a4[0]=f2bf(ra[it].x); a4[1]=f2bf(ra[it].y); a4[2]=f2bf(ra[it].z); a4[3]=f2bf(ra[it].w);
            *(bf16x4*)(sA + f) = a4;
            bf16x4 b4; b4[0]=f2bf(rb[it].x); b4[1]=f2bf(rb[it].y); b4[2]=f2bf(rb[it].z); b4[3]=f2bf(rb[it].w);
            *(bf16x4*)(sB + f) = b4;
        }
        __syncthreads();                        // staged visible
        if (kc + 128 < DDIM) {                  // prefetch kc+1 (in flight under MFMA)
            #pragma unroll
            for (int it = 0; it < 8; ++it) {
                int f = it*1024 + tid*4, row = f >> 7, col = f & 127;
                ra[it] = *(const float4*)(A  + (size_t)(m0+row)*DDIM + kc + 128 + col);
                rb[it] = *(const float4*)(Bm + (size_t)(n0+row)*DDIM + kc + 128 + col);
            }
        }
        #pragma unroll
        for (int t = 0; t < 4; ++t) {
            bf16x8 af = *(const bf16x8*)(sA + (wave*16 + l15)*128 + t*32 + quad*8);
            #pragma unroll
            for (int n = 0; n < 4; ++n) {
                bf16x8 bfr = *(const bf16x8*)(sB + (n*16 + l15)*128 + t*32 + quad*8);
                acc[n] = __builtin_amdgcn_mfma_f32_16x16x32_bf16(af, bfr, acc[n], 0, 0, 0);
            }
        }
    }
    #pragma unroll
    for (int n = 0; n < 4; ++n)
        #pragma unroll
        for (int r = 0; r < 4; ++r) {
            int m  = m0 + wave*16 + quad*4 + r;
            int nn = n0 + n*16 + l15;
            C[(size_t)m*N + nn] = (unsigned short)f2bf(acc[n][r]);
        }
}

// ---------------------------------------------------------------------------
// Fused attention, R4: back to 2 blocks/CU for pipe overlap (R3 diagnosis:
// 1 block x 8 lockstep waves ran LDS/MFMA/VALU pipes serially; the sibling
// block anti-phases them). Block = 4 waves (wm=0..1 x wk=0..1) x 64 Q-rows,
// grid = 512; LDS 73 KB so 2 blocks fit. K dbuf (depth-1 prefetch is enough:
// K is L2-resident via the XCD-split swizzle, ~300 cyc). Counted-vmcnt
// barriers kept from R3 (c1 keeps V's 8 loads in flight). Per-wave math
// (frag-linear QK reads, in-lane softmax, P-exchange, dv-split PV)
// unchanged since R2 (verified, absmax 9.8e-4).
// ---------------------------------------------------------------------------
__global__ __launch_bounds__(256, 2) void attn_fused(
    const float* __restrict__ X,            // [16384][512] fp32
    const unsigned short* __restrict__ Kb,  // key bf16 [4096][512] natural
    const unsigned short* __restrict__ Vt,  // V^T bf16 [256][4096] natural
    float* __restrict__ Opart,              // [NS][16384][256]
    float* __restrict__ Mpart,              // [NS][16384]
    float* __restrict__ Lpart)              // [NS][16384]
{
    // 0     : K dbuf 2 x 16KB frag-linear (tile T=(drow<<1)|kh, 1KB each)
    // 32768 : sV 32KB frag-linear (tile T=(nn<<2)|g)
    // 65536 : sPex 8KB [wm=2][g=4][lane]x16B
    // 73728 : sSt 1KB [wave=4][slot=2][32] floats
    __shared__ __align__(16) char smem[74752];
    char* b0   = smem;
    char* b1   = smem + 16384;
    char* sV   = smem + 32768;
    char* sPex = smem + 65536;
    float* sSt = (float*)(smem + 73728);

    const int tid  = threadIdx.x;
    const int wave = tid >> 6;      // 0..3
    const int lane = tid & 63;
    const int l31  = lane & 31;
    const int hi   = lane >> 5;
    const int wm   = wave >> 1;     // 0..1: Q-row group
    const int wk   = wave & 1;      // key-half for QK / dv-half for PV

    // XCD-split swizzle: bid&7 = XCD; XCD 0-3 -> split 0, 4-7 -> split 1.
    // Per-XCD K+V working set = 3 MB < 4 MB L2 -> L2-resident staging.
    const int bid   = blockIdx.x;          // 0..511
    const int xcd   = bid & 7;
    const int slot  = bid >> 3;            // 0..63
    const int split = xcd >> 2;
    const int q0    = ((xcd & 3)*64 + slot) * 64;
    const float scale = 0.04419417382415922f;  // 1/sqrt(512)

    // Q as MFMA B-frags (swapped QK: B[k=d][col=q]), scale folded. 128 VGPR.
    bf16x8 qf[32];
    {
        const float* xrow = X + (size_t)(q0 + wm*32 + l31)*DDIM + hi*8;
        #pragma unroll
        for (int t = 0; t < 32; ++t) {
            float4 a = *(const float4*)(xrow + t*16);
            float4 b = *(const float4*)(xrow + t*16 + 4);
            bf16x8 q;
            q[0]=f2bf(a.x*scale); q[1]=f2bf(a.y*scale); q[2]=f2bf(a.z*scale); q[3]=f2bf(a.w*scale);
            q[4]=f2bf(b.x*scale); q[5]=f2bf(b.y*scale); q[6]=f2bf(b.z*scale); q[7]=f2bf(b.w*scale);
            qf[t] = q;
        }
    }

    // O acc: D[row=q][col=dv], wave's dv-half = wk*128 + n*32 + l31. 64 VGPR.
    f32x16 o[4];
    #pragma unroll
    for (int n = 0; n < 4; ++n)
        #pragma unroll
        for (int r = 0; r < 16; ++r) o[n][r] = 0.f;
    float m_r = -1e30f, l_r = 0.f;       // shared across wk pair (joint max)

    const int jt0 = split * (NJ*64);

    // stage K chunk cc (128 d) of 64-key tile jtb_ frag-linear into bufp_.
    // 16 tiles of 1KB; 4 waves stage 4 each. Tile T=(drow<<1)|kh:
    // drow = wave*2 + (it>>1), kh = it&1.
    #define STAGE_K(jtb_, cc_, bufp_)                                         \
        do {                                                                  \
            _Pragma("unroll")                                                 \
            for (int it_ = 0; it_ < 4; ++it_) {                               \
                const char* src_ = (const char*)Kb                            \
                    + (size_t)((jtb_) + (it_&1)*32 + l31)*1024                \
                    + (cc_)*256 + wave*64 + (it_>>1)*32 + hi*16;              \
                gload_lds16(src_, (bufp_) + (wave*4 + it_)*1024);             \
            }                                                                 \
        } while (0)

    // stage V^T tile frag-linear: 32 tiles of 1KB; 4 waves stage 8 each.
    // Tile T=(nn<<2)|g: nn = wave*2 + (it>>2), g = it&3.
    #define STAGE_V(jtb_)                                                     \
        do {                                                                  \
            _Pragma("unroll")                                                 \
            for (int it_ = 0; it_ < 8; ++it_) {                               \
                const char* src_ = (const char*)Vt                            \
                    + (size_t)((wave*2 + (it_>>2))*32 + l31)*8192             \
                    + (size_t)((jtb_) + (it_&3)*16 + hi*8)*2;                 \
                gload_lds16(src_, sV + (wave*8 + it_)*1024);                  \
            }                                                                 \
        } while (0)

    // QK phase: 8 MFMAs on chunk cc from bufp_ (frag-linear, lane-linear reads)
    #define QK8(cc_, bufp_)                                                   \
        do {                                                                  \
            const char* kb_ = (bufp_) + wk*1024 + lane*16;                    \
            __builtin_amdgcn_s_setprio(1);                                    \
            _Pragma("unroll")                                                 \
            for (int t_ = 0; t_ < 8; ++t_) {                                  \
                bf16x8 kf_ = *(const bf16x8*)(kb_ + t_*2048);                 \
                s = __builtin_amdgcn_mfma_f32_32x32x16_bf16(                  \
                        kf_, qf[(cc_)*8 + t_], s, 0, 0, 0);                   \
            }                                                                 \
            __builtin_amdgcn_s_setprio(0);                                    \
        } while (0)

    STAGE_K(jt0, 0, b0);                // prologue chunk 0 -> b0

    for (int j = 0; j < NJ; ++j) {
        const int jtb = jt0 + j*64;
        f32x16 s;                       // P^T acc: D[row=key][col=q]
        #pragma unroll
        for (int r = 0; r < 16; ++r) s[r] = 0.f;

        // ---- c0: drain K(c0); issue K(c1)->b1 then V; QK(c0) from b0 ----
        BAR_VM(0);
        STAGE_K(jtb, 1, b1);            // issued FIRST (oldest -> drained at c1)
        STAGE_V(jtb);                   // 8 loads, kept in flight at c1
        QK8(0, b0);
        // ---- c1: drain K(c1) only (vmcnt(8) keeps V); issue K(c2)->b0 ----
        BAR_VM(8);
        STAGE_K(jtb, 2, b0);
        QK8(1, b1);
        // ---- c2: drain K(c2)+V; issue K(c3)->b1 ----
        BAR_VM(0);
        STAGE_K(jtb, 3, b1);
        QK8(2, b0);
        // ---- c3: drain K(c3); issue next-j K(c0)->b0 (in flight across
        //      softmax+PV, drained by next j's c0 barrier) ----
        BAR_VM(0);
        if (j + 1 < NJ) STAGE_K(jtb + 64, 0, b0);
        QK8(3, b1);

        // ---- softmax: in-lane (lane owns q=l31; 16 keys + hi-partner via
        //      shfl_xor(32)), then joint max across wk pair via LDS ----
        float tmax = fmaxf(fmaxf(fmaxf(s[0],s[1]),fmaxf(s[2],s[3])),
                           fmaxf(fmaxf(s[4],s[5]),fmaxf(s[6],s[7])));
        tmax = fmaxf(tmax, fmaxf(fmaxf(fmaxf(s[8],s[9]),fmaxf(s[10],s[11])),
                                 fmaxf(fmaxf(s[12],s[13]),fmaxf(s[14],s[15]))));
        tmax = fmaxf(tmax, __shfl_xor(tmax, 32));
        if (lane < 32) sSt[(wave*2 + 0)*32 + lane] = tmax;
        BAR_LGKM();                                             // exchange 1
        float tmax_o = sSt[((wave^1)*2 + 0)*32 + l31];
        const float mn = fmaxf(m_r, fmaxf(tmax, tmax_o));
        const float alpha = __expf(m_r - mn);
        float tsum = 0.f;
        #pragma unroll
        for (int r = 0; r < 16; ++r) { float pv = __expf(s[r] - mn); s[r] = pv; tsum += pv; }
        tsum += __shfl_xor(tsum, 32);

        // P -> PV A-frags in-register (cvt_pk + permlane32_swap, proven R1-R3)
        bf16x8 pf[2];
        #pragma unroll
        for (int ks = 0; ks < 2; ++ks) {
            int wA, wB, wC, wD;
            asm("v_cvt_pk_bf16_f32 %0, %1, %2" : "=v"(wA) : "v"(s[8*ks+0]), "v"(s[8*ks+1]));
            asm("v_cvt_pk_bf16_f32 %0, %1, %2" : "=v"(wB) : "v"(s[8*ks+2]), "v"(s[8*ks+3]));
            asm("v_cvt_pk_bf16_f32 %0, %1, %2" : "=v"(wC) : "v"(s[8*ks+4]), "v"(s[8*ks+5]));
            asm("v_cvt_pk_bf16_f32 %0, %1, %2" : "=v"(wD) : "v"(s[8*ks+6]), "v"(s[8*ks+7]));
            asm("v_permlane32_swap_b32 %0, %1" : "+v"(wA), "+v"(wC));
            asm("v_permlane32_swap_b32 %0, %1" : "+v"(wB), "+v"(wD));
            union { int w[4]; bf16x8 v; } u;
            u.w[0] = wA; u.w[1] = wB; u.w[2] = wC; u.w[3] = wD;
            pf[ks] = u.v;
        }
        *(bf16x8*)(sPex + (wm*4 + wk*2 + 0)*1024 + lane*16) = pf[0];
        *(bf16x8*)(sPex + (wm*4 + wk*2 + 1)*1024 + lane*16) = pf[1];
        if (lane < 32) sSt[(wave*2 + 1)*32 + lane] = tsum;
        BAR_LGKM();                                             // exchange 2
        float tsum_o = sSt[((wave^1)*2 + 1)*32 + l31];
        l_r = l_r*alpha + (tsum + tsum_o);
        m_r = mn;
        if (__any(alpha < 1.f)) {       // rescale O (alpha indexed by q-row)
            #pragma unroll
            for (int r = 0; r < 16; ++r) {
                int row = (r&3) + 8*(r>>2) + 4*hi;
                float ar = __shfl(alpha, row);
                #pragma unroll
                for (int n = 0; n < 4; ++n) o[n][r] *= ar;
            }
        }

        // ---- PV: O[dv-half wk] += P(all 64 keys) * V^T; lane-linear reads ----
        const char* vb = sV + wk*16384 + lane*16;
        const char* pb = sPex + wm*4096 + lane*16;
        __builtin_amdgcn_s_setprio(1);
        #pragma unroll
        for (int g = 0; g < 4; ++g) {
            bf16x8 pa = ((g >> 1) == wk) ? pf[g & 1]
                        : *(const bf16x8*)(pb + g*1024);
            #pragma unroll
            for (int n = 0; n < 4; ++n) {
                bf16x8 vf = *(const bf16x8*)(vb + (n*4 + g)*1024);
                o[n] = __builtin_amdgcn_mfma_f32_32x32x16_bf16(pa, vf, o[n], 0, 0, 0);
            }
        }
        __builtin_amdgcn_s_setprio(0);
    }
    #undef STAGE_K
    #undef STAGE_V
    #undef QK8

    // ---- epilogue: shared (m,l) across wk; disjoint dv halves -> no merge ----
    const size_t base = (size_t)split * NROWS;
    const int gr0 = q0 + wm*32;
    if (wk == 0 && lane < 32) {
        Mpart[base + gr0 + lane] = m_r;
        Lpart[base + gr0 + lane] = l_r;
    }
    #pragma unroll
    for (int r = 0; r < 16; ++r) {
        int row = (r&3) + 8*(r>>2) + 4*hi;
        float* orow = Opart + (base + gr0 + row) * (size_t)DVDIM + wk*128;
        #pragma unroll
        for (int n = 0; n < 4; ++n)
            orow[n*32 + l31] = o[n][r];
    }
}

// ---------------------------------------------------------------------------
// Combine NS split partials: out = sum_s(Os*ws) / sum_s(ls*ws), ws=exp(ms-M).
// grid = NROWS/4, block = 256: 4 rows/block, one float4 per thread. Coalesced.
// ---------------------------------------------------------------------------
__global__ void combine_splits(
    const float* __restrict__ Opart, const float* __restrict__ Mpart,
    const float* __restrict__ Lpart, float* __restrict__ out)
{
    const int row = blockIdx.x * 4 + (threadIdx.x >> 6);
    const int dv4 = (threadIdx.x & 63) * 4;
    float M = -1e30f;
    #pragma unroll
    for (int s = 0; s < NS; ++s) M = fmaxf(M, Mpart[(size_t)s*NROWS + row]);
    float denom = 0.f;
    float4 acc = make_float4(0.f, 0.f, 0.f, 0.f);
    #pragma unroll
    for (int s = 0; s < NS; ++s) {
        float w = __expf(Mpart[(size_t)s*NROWS + row] - M);
        denom += Lpart[(size_t)s*NROWS + row] * w;
        float4 ov = *(const float4*)(Opart + ((size_t)s*NROWS + row)*DVDIM + dv4);
        acc.x += ov.x*w; acc.y += ov.y*w; acc.z += ov.z*w; acc.w += ov.w*w;
    }
    float inv = 1.0f / denom;
    *(float4*)(out + (size_t)row*DVDIM + dv4)
        = make_float4(acc.x*inv, acc.y*inv, acc.z*inv, acc.w*inv);
}

extern "C" void kernel_launch(void* const* d_in, const int* in_sizes, int n_in,
                              void* d_out, int out_size, void* d_ws, size_t ws_size,
                              hipStream_t stream) {
    const float* X  = (const float*)d_in[0];   // [8,2048,512]
    const float* Y  = (const float*)d_in[1];   // [4096,512]
    const float* Z  = (const float*)d_in[2];   // [4096,512]
    const float* Wk = (const float*)d_in[3];   // [512,512]
    const float* Wv = (const float*)d_in[4];   // [256,512]
    float* out = (float*)d_out;

    // workspace layout (~38.3 MB)
    char* ws = (char*)d_ws;
    unsigned short* keyb = (unsigned short*)ws;                    // 4 MB, natural [4096][512]
    unsigned short* vtb  = (unsigned short*)(ws + (4u<<20));       // 2 MB, natural [256][4096]
    float* Opart = (float*)(ws + (6u<<20));                        // NS x 16 MB
    float* Mpart = (float*)(ws + (6u<<20) + (size_t)NS*NROWS*DVDIM*4);
    float* Lpart = Mpart + (size_t)NS*NROWS;

    // both projections, one launch
    proj_gemms<<<dim3(64, 8, 2), dim3(256), 0, stream>>>(Y, Z, Wk, Wv, keyb, vtb);
    // fused attention: 512 blocks (2/CU for pipe overlap), 4 waves each
    attn_fused<<<dim3(512), dim3(256), 0, stream>>>(
        X, keyb, vtb, Opart, Mpart, Lpart);
    // merge splits
    combine_splits<<<dim3(NROWS/4), dim3(256), 0, stream>>>(Opart, Mpart, Lpart, out);
}